// Round 10
// baseline (156.992 us; speedup 1.0000x reference)
//
#include <hip/hip_runtime.h>

typedef unsigned short u16;
typedef unsigned int   u32;
typedef unsigned long long u64;
typedef short  short8 __attribute__((ext_vector_type(8)));
typedef float  f32x2  __attribute__((ext_vector_type(2)));
typedef float  f32x4  __attribute__((ext_vector_type(4)));
typedef float  f32x16 __attribute__((ext_vector_type(16)));
typedef u16    u16x4  __attribute__((ext_vector_type(4)));

__device__ __forceinline__ u16 f2b(float f) {
    u32 u = __float_as_uint(f);
    u32 r = (u + 0x7fffu + ((u >> 16) & 1u)) >> 16;  // RNE to bf16
    return (u16)r;
}

__device__ __forceinline__ u32 cvtpk(float a, float b) {
    u32 r;
    asm("v_cvt_pk_bf16_f32 %0, %1, %2" : "=v"(r) : "v"(a), "v"(b));
    return r;  // lo = bf16(a), hi = bf16(b)
}

__device__ __forceinline__ float ex2(float x) {   // 2^x, native v_exp_f32
    float r;
    asm("v_exp_f32 %0, %1" : "=v"(r) : "v"(x));
    return r;
}

__device__ __forceinline__ f32x2 pkfma(f32x2 a, f32x2 b, f32x2 c) {  // a*b+c per half
    f32x2 d;
    asm("v_pk_fma_f32 %0, %1, %2, %3" : "=v"(d) : "v"(a), "v"(b), "v"(c));
    return d;
}

// swap a's upper 32 lanes with c's lower 32 lanes
__device__ __forceinline__ void pl32swap(u32& a, u32& c) {
    asm("v_permlane32_swap_b32 %0, %1" : "+v"(a), "+v"(c));
}

__device__ __forceinline__ void gload_lds16(const void* g, void* l) {
    __builtin_amdgcn_global_load_lds(
        (const __attribute__((address_space(1))) u32*)g,
        (__attribute__((address_space(3))) u32*)l,
        16, 0, 0);
}

// ---------------- fused fp32 -> bf16 casts (one launch) ----------------
#define N4X 1048576   // 4096*1024/4
#define N4Q  786432   // 3*1024*1024/4
#define N4P  262144   // 1024*1024/4
__global__ __launch_bounds__(256) void cvt_all(
    const float* __restrict__ x, const float* __restrict__ wq, const float* __restrict__ wp,
    u16* __restrict__ xb, u16* __restrict__ wqb, u16* __restrict__ wpb)
{
    const int i = blockIdx.x * 256 + threadIdx.x;
    const float* src; u16* dst; int j;
    if (i < N4X)            { src = x;  dst = xb;  j = i; }
    else if (i < N4X + N4Q) { src = wq; dst = wqb; j = i - N4X; }
    else                    { src = wp; dst = wpb; j = i - N4X - N4Q; }
    float4 v = ((const float4*)src)[j];
    u16x4 r = { f2b(v.x), f2b(v.y), f2b(v.z), f2b(v.w) };
    ((u16x4*)dst)[j] = r;
}

// ---------------- C = A @ B^T, 128x128 tile (round-2 verified, verbatim) ----------------
__global__ __launch_bounds__(256) void gemm_bt(
    const u16* __restrict__ A, const u16* __restrict__ Bm,
    u16* __restrict__ Cb, float* __restrict__ Cf, const float* __restrict__ bias,
    int M, int N, int K)
{
    __shared__ __align__(16) u16 As[128*32];
    __shared__ __align__(16) u16 Bs[128*32];
    const int t = threadIdx.x;
    const int w = t >> 6, lane = t & 63;
    const int l15 = lane & 15, lg = lane >> 4;
    const int m0 = blockIdx.y * 128, n0 = blockIdx.x * 128;
    const int wr = w >> 1, wc = w & 1;
    f32x4 acc[4][4] = {};

    for (int kt = 0; kt < K; kt += 32) {
        #pragma unroll
        for (int j = 0; j < 2; ++j) {
            const int c   = j*256 + t;
            const int row = c >> 2, colb = (c & 3) * 8;
            gload_lds16(&A [(size_t)(m0+row)*K + kt + colb], &As[(size_t)(j*256 + w*64)*8]);
            gload_lds16(&Bm[(size_t)(n0+row)*K + kt + colb], &Bs[(size_t)(j*256 + w*64)*8]);
        }
        __syncthreads();
        short8 af[4], bfr[4];
        #pragma unroll
        for (int mi = 0; mi < 4; ++mi)
            af[mi] = *(const short8*)&As[(wr*64 + mi*16 + l15)*32 + lg*8];
        #pragma unroll
        for (int ni = 0; ni < 4; ++ni)
            bfr[ni] = *(const short8*)&Bs[(wc*64 + ni*16 + l15)*32 + lg*8];
        #pragma unroll
        for (int mi = 0; mi < 4; ++mi)
            #pragma unroll
            for (int ni = 0; ni < 4; ++ni)
                acc[mi][ni] = __builtin_amdgcn_mfma_f32_16x16x32_bf16(af[mi], bfr[ni], acc[mi][ni], 0, 0, 0);
        __syncthreads();
    }

    #pragma unroll
    for (int mi = 0; mi < 4; ++mi) {
        #pragma unroll
        for (int ni = 0; ni < 4; ++ni) {
            const int row = m0 + wr*64 + mi*16 + lg*4;
            const int col = n0 + wc*64 + ni*16 + l15;
            if (Cb) {
                #pragma unroll
                for (int r = 0; r < 4; ++r)
                    Cb[(size_t)(row+r)*N + col] = f2b(acc[mi][ni][r]);
            } else {
                const float bv = bias ? bias[col] : 0.f;
                #pragma unroll
                for (int r = 0; r < 4; ++r)
                    Cf[(size_t)(row+r)*N + col] = acc[mi][ni][r] + bv;
            }
        }
    }
}

// ---------------- C = A @ B^T, 64x128 tile (round-8 verified, verbatim) ----------------
__global__ __launch_bounds__(256) void gemm_bt64(
    const u16* __restrict__ A, const u16* __restrict__ Bm,
    float* __restrict__ Cf, const float* __restrict__ bias,
    int M, int N, int K)
{
    __shared__ __align__(16) u16 As[64*32];
    __shared__ __align__(16) u16 Bs[128*32];
    const int t = threadIdx.x;
    const int w = t >> 6, lane = t & 63;
    const int l15 = lane & 15, lg = lane >> 4;
    const int m0 = blockIdx.y * 64, n0 = blockIdx.x * 128;
    const int wr = w >> 1, wc = w & 1;
    f32x4 acc[2][4] = {};

    for (int kt = 0; kt < K; kt += 32) {
        gload_lds16(&A[(size_t)(m0 + w*16 + (lane >> 2))*K + kt + (lane & 3)*8],
                    &As[(size_t)w*512]);
        #pragma unroll
        for (int j = 0; j < 2; ++j) {
            const int c   = j*256 + t;
            const int row = c >> 2, colb = (c & 3) * 8;
            gload_lds16(&Bm[(size_t)(n0+row)*K + kt + colb], &Bs[(size_t)(j*256 + w*64)*8]);
        }
        __syncthreads();
        short8 af[2], bfr[4];
        #pragma unroll
        for (int mi = 0; mi < 2; ++mi)
            af[mi] = *(const short8*)&As[(wr*32 + mi*16 + l15)*32 + lg*8];
        #pragma unroll
        for (int ni = 0; ni < 4; ++ni)
            bfr[ni] = *(const short8*)&Bs[(wc*64 + ni*16 + l15)*32 + lg*8];
        #pragma unroll
        for (int mi = 0; mi < 2; ++mi)
            #pragma unroll
            for (int ni = 0; ni < 4; ++ni)
                acc[mi][ni] = __builtin_amdgcn_mfma_f32_16x16x32_bf16(af[mi], bfr[ni], acc[mi][ni], 0, 0, 0);
        __syncthreads();
    }

    #pragma unroll
    for (int mi = 0; mi < 2; ++mi) {
        #pragma unroll
        for (int ni = 0; ni < 4; ++ni) {
            const int row = m0 + wr*32 + mi*16 + lg*4;
            const int col = n0 + wc*64 + ni*16 + l15;
            const float bv = bias ? bias[col] : 0.f;
            #pragma unroll
            for (int r = 0; r < 4; ++r)
                Cf[(size_t)(row+r)*N + col] = acc[mi][ni][r] + bv;
        }
    }
}

// ---------------- fused masked flash attention v7: deferred-PV pipeline (T15) ----------------
// r9 math, restructured: double-buffered Ks/Vt; PV(t-1) runs in body(t) so its MFMAs
// overlap SM(t)'s VALU; barrier1 = lgkmcnt-only s_barrier (prefetches stay in flight);
// barrier2 = __syncthreads. PV(t-1) precedes the (rare) rescale(t) -> math identical.
__global__ __launch_bounds__(256) void attn_v7(
    const u16* __restrict__ qkv,   // [B*N][3072] bf16
    const int* __restrict__ mask,  // [B*N]
    u16* __restrict__ aout)        // [B*N][1024] bf16
{
    __shared__ __align__(16) u16 Ks[2][64*64];   // [kv][d], chunk ^= kv&7
    __shared__ __align__(16) u16 Vt[2][64*64];   // [d][kv], chunk ^= (d^(d>>3))&7

    const int t = threadIdx.x, w = t >> 6, lane = t & 63;
    const int l31 = lane & 31, hi = lane >> 5;

    const int wid = ((blockIdx.x & 7) << 6) | (blockIdx.x >> 3);   // XCD-contiguous
    const int qt = wid & 15, h = (wid >> 4) & 15, b = wid >> 8;
    const int q0 = qt * 128 + w * 32;
    const int kvb = b * 2048;

    const size_t qrow = (size_t)(kvb + q0 + l31);
    short8 qf[4];
    #pragma unroll
    for (int i = 0; i < 4; ++i)
        qf[i] = *(const short8*)&qkv[qrow*3072 + h*64 + i*16 + hi*8];
    const int mq = mask[kvb + q0 + l31];
    const float qs2 = mq ? 0.18033688011f : 0.f;   // 0.125 * log2(e); 0 -> uniform row

    union { u32 u[4]; short8 s; } qe;
    qe.u[0] = hi ? 0u : 0x3F80u;   // bf16 1.0 in k-slot 0
    qe.u[1] = 0; qe.u[2] = 0; qe.u[3] = 0;

    float m2 = -3e38f, l_run = 0.f;    // m2 in log2-scaled units
    f32x16 oacc[2] = {};

    const int vrr = t >> 3, vc8 = t & 7;
    const int kri = lane >> 3;
    const int scK = ((lane & 7) ^ (lane >> 3)) * 8;

    // ---- prologue: stage tile 0 into buf0, prefetch V(1), ballot(0) ----
    {
        const u16* p = qkv + (size_t)(kvb + vrr)*3072 + 2048 + h*64 + vc8*8;
        const short8 va = *(const short8*)p;
        const short8 vb2 = *(const short8*)(p + (size_t)32*3072);
        #pragma unroll
        for (int pp = 0; pp < 2; ++pp) {
            const int kv = pp*32 + vrr;
            const int kvhi = kv >> 3, kvlo = kv & 7;
            const short8 v = pp ? vb2 : va;
            #pragma unroll
            for (int j = 0; j < 8; ++j)
                Vt[0][(vc8*8 + j)*64 + ((kvhi ^ ((j ^ vc8) & 7)) << 3) + kvlo] = (u16)v[j];
        }
    }
    #pragma unroll
    for (int i = 0; i < 2; ++i)
        gload_lds16(&qkv[(size_t)(kvb + w*16 + i*8 + kri)*3072 + 1024 + h*64 + scK],
                    &Ks[0][(w*16 + i*8)*64]);
    short8 vn0, vn1;
    {
        const u16* p = qkv + (size_t)(kvb + 64 + vrr)*3072 + 2048 + h*64 + vc8*8;
        vn0 = *(const short8*)p;
        vn1 = *(const short8*)(p + (size_t)32*3072);
    }
    {
        const u64 bal0 = __ballot(mask[kvb + lane] != 0);
        __syncthreads();   // tile 0 staged
        // keep ballot in scope below
        u32 mwA = (u32)bal0, mwB = (u32)(bal0 >> 32);
        u32 o_prev[16];
        #pragma unroll
        for (int i = 0; i < 16; ++i) o_prev[i] = 0;

        for (int it = 0; it < 32; ++it) {
            u16* __restrict__ KsB = Ks[it & 1];
            u16* __restrict__ VtP = Vt[(it + 1) & 1];   // holds V(it-1); becomes V(it+1)
            u16* __restrict__ KsN = Ks[(it + 1) & 1];
            const int t1 = (it + 1 < 32) ? it + 1 : 31;
            const int t2 = (it + 2 < 32) ? it + 2 : 31;

            // ---- 1. QK^T(it) + mask-bias ----
            f32x16 st0 = {}, st1 = {};
            __builtin_amdgcn_s_setprio(1);
            #pragma unroll
            for (int kd = 0; kd < 4; ++kd) {
                const int c = (2*kd + hi) ^ (l31 & 7);
                short8 kf0 = *(const short8*)&KsB[ l31      *64 + c*8];
                short8 kf1 = *(const short8*)&KsB[(32 + l31)*64 + c*8];
                st0 = __builtin_amdgcn_mfma_f32_32x32x16_bf16(kf0, qf[kd], st0, 0, 0, 0);
                st1 = __builtin_amdgcn_mfma_f32_32x32x16_bf16(kf1, qf[kd], st1, 0, 0, 0);
            }
            {
                union { u32 u[4]; short8 s; } ba0, ba1;
                ba0.u[0] = (((mwA >> l31) & 1u) | (u32)hi) ? 0u : 0xFF7Fu;  // bf16 -3.3895e38
                ba1.u[0] = (((mwB >> l31) & 1u) | (u32)hi) ? 0u : 0xFF7Fu;
                ba0.u[1] = 0; ba0.u[2] = 0; ba0.u[3] = 0;
                ba1.u[1] = 0; ba1.u[2] = 0; ba1.u[3] = 0;
                st0 = __builtin_amdgcn_mfma_f32_32x32x16_bf16(ba0.s, qe.s, st0, 0, 0, 0);
                st1 = __builtin_amdgcn_mfma_f32_32x32x16_bf16(ba1.s, qe.s, st1, 0, 0, 0);
            }
            __builtin_amdgcn_s_setprio(0);

            // ---- 1b. prefetch V(it+2) + mask(it+1) (stay in flight across barrier1) ----
            short8 vp0, vp1;
            {
                const u16* p = qkv + (size_t)(kvb + t2*64 + vrr)*3072 + 2048 + h*64 + vc8*8;
                vp0 = *(const short8*)p;
                vp1 = *(const short8*)(p + (size_t)32*3072);
            }
            const u64 baln = __ballot(mask[kvb + t1*64 + lane] != 0);

            // ---- 2. PV(it-1): MFMA, overlaps SM below across iterations ----
            if (it) {
                __builtin_amdgcn_s_setprio(1);
                #pragma unroll
                for (int kk = 0; kk < 4; ++kk) {
                    const int base = (kk >> 1)*8 + (kk & 1)*4;
                    u32 a0 = o_prev[base],   c0 = o_prev[base+2];
                    u32 a1 = o_prev[base+1], c1 = o_prev[base+3];
                    pl32swap(a0, c0);
                    pl32swap(a1, c1);
                    union { u32 u[4]; short8 s; } pa;
                    pa.u[0] = a0; pa.u[1] = a1; pa.u[2] = c0; pa.u[3] = c1;
                    #pragma unroll
                    for (int dt = 0; dt < 2; ++dt) {
                        const int d = dt*32 + l31;
                        const int c = (2*kk + hi) ^ ((d ^ (d >> 3)) & 7);
                        short8 vf = *(const short8*)&VtP[d*64 + c*8];
                        oacc[dt] = __builtin_amdgcn_mfma_f32_32x32x16_bf16(pa.s, vf, oacc[dt], 0, 0, 0);
                    }
                }
                __builtin_amdgcn_s_setprio(0);
            }

            // ---- 3. barrier1: LDS reads done; NO vmem drain ----
            asm volatile("s_waitcnt lgkmcnt(0)" ::: "memory");
            __builtin_amdgcn_s_barrier();
            __builtin_amdgcn_sched_barrier(0);

            // ---- 4. stage(it+1): V regs -> VtP, K dma -> KsN ----
            #pragma unroll
            for (int pp = 0; pp < 2; ++pp) {
                const int kv = pp*32 + vrr;
                const int kvhi = kv >> 3, kvlo = kv & 7;
                const short8 v = pp ? vn1 : vn0;
                #pragma unroll
                for (int j = 0; j < 8; ++j)
                    VtP[(vc8*8 + j)*64 + ((kvhi ^ ((j ^ vc8) & 7)) << 3) + kvlo] = (u16)v[j];
            }
            #pragma unroll
            for (int i = 0; i < 2; ++i)
                gload_lds16(&qkv[(size_t)(kvb + t1*64 + w*16 + i*8 + kri)*3072 + 1024 + h*64 + scK],
                            &KsN[(w*16 + i*8)*64]);

            // ---- 5. SM(it): max, defer-rescale (after PV: program order), exp, pack ----
            float pm0 = -3e38f, pm1 = -3e38f, pm2 = -3e38f, pm3 = -3e38f;
            #pragma unroll
            for (int r = 0; r < 16; r += 4) {
                pm0 = fmaxf(pm0, fmaxf(st0[r],   st1[r]));
                pm1 = fmaxf(pm1, fmaxf(st0[r+1], st1[r+1]));
                pm2 = fmaxf(pm2, fmaxf(st0[r+2], st1[r+2]));
                pm3 = fmaxf(pm3, fmaxf(st0[r+3], st1[r+3]));
            }
            const float pmx = fmaxf(fmaxf(pm0, pm1), fmaxf(pm2, pm3));

            if (__any(fmaf(pmx, qs2, -m2) > 11.5f)) {
                float pml = pmx * qs2;
                pml = fmaxf(pml, __shfl_xor(pml, 32));
                const float m_new = fmaxf(m2, pml);
                const float alpha = ex2(m2 - m_new);
                l_run *= alpha;
                #pragma unroll
                for (int r = 0; r < 16; ++r) {
                    const int pat = (r & 3) + 8*(r >> 2);
                    const float ar = __shfl(alpha, pat + 4*hi);
                    oacc[0][r] *= ar; oacc[1][r] *= ar;
                }
                m2 = m_new;
            }

            const float nm = -m2;
            const f32x2 qv = { qs2, qs2 };
            const f32x2 nv = { nm, nm };
            float rs0 = 0.f, rs1 = 0.f;
            #pragma unroll
            for (int i = 0; i < 8; ++i) {
                f32x2 s0p = { st0[2*i], st0[2*i+1] };
                f32x2 s1p = { st1[2*i], st1[2*i+1] };
                const f32x2 d0 = pkfma(s0p, qv, nv);
                const f32x2 d1 = pkfma(s1p, qv, nv);
                const float p0 = ex2(d0.x), p1 = ex2(d0.y);
                const float p2 = ex2(d1.x), p3 = ex2(d1.y);
                o_prev[i]     = cvtpk(p0, p1);
                o_prev[8 + i] = cvtpk(p2, p3);
                rs0 += p0 + p1;
                rs1 += p2 + p3;
            }
            float rs = rs0 + rs1;
            rs += __shfl_xor(rs, 32);
            l_run += rs;

            vn0 = vp0; vn1 = vp1;
            mwA = (u32)baln; mwB = (u32)(baln >> 32);

            __syncthreads();   // barrier2: staged tile it+1 visible
        }

        // ---- epilogue: final PV(31) from Vt[1] (intact), then normalize ----
        {
            u16* __restrict__ VtL = Vt[1];
            #pragma unroll
            for (int kk = 0; kk < 4; ++kk) {
                const int base = (kk >> 1)*8 + (kk & 1)*4;
                u32 a0 = o_prev[base],   c0 = o_prev[base+2];
                u32 a1 = o_prev[base+1], c1 = o_prev[base+3];
                pl32swap(a0, c0);
                pl32swap(a1, c1);
                union { u32 u[4]; short8 s; } pa;
                pa.u[0] = a0; pa.u[1] = a1; pa.u[2] = c0; pa.u[3] = c1;
                #pragma unroll
                for (int dt = 0; dt < 2; ++dt) {
                    const int d = dt*32 + l31;
                    const int c = (2*kk + hi) ^ ((d ^ (d >> 3)) & 7);
                    short8 vf = *(const short8*)&VtL[d*64 + c*8];
                    oacc[dt] = __builtin_amdgcn_mfma_f32_32x32x16_bf16(pa.s, vf, oacc[dt], 0, 0, 0);
                }
            }
        }

        const float inv = 1.f / l_run;
        #pragma unroll
        for (int r = 0; r < 16; ++r) {
            const int pat = (r & 3) + 8*(r >> 2);
            const float ir = __shfl(inv, pat + 4*hi);
            const size_t rowg = (size_t)(kvb + q0 + pat + 4*hi);
            aout[rowg*1024 + h*64 +      l31] = f2b(oacc[0][r] * ir);
            aout[rowg*1024 + h*64 + 32 + l31] = f2b(oacc[1][r] * ir);
        }
    }
}

extern "C" void kernel_launch(void* const* d_in, const int* in_sizes, int n_in,
                              void* d_out, int out_size, void* d_ws, size_t ws_size,
                              hipStream_t stream)
{
    (void)in_sizes; (void)n_in; (void)out_size; (void)ws_size;
    const float* x      = (const float*)d_in[0];
    const int*   mask   = (const int*)  d_in[1];
    const float* w_qkv  = (const float*)d_in[2];
    const float* w_proj = (const float*)d_in[3];
    const float* b_proj = (const float*)d_in[4];
    float* out = (float*)d_out;

    const int M = 4096;   // B*N
    const int C = 1024;

    u16* xb   = (u16*)d_ws;                    // M*C
    u16* wqb  = xb   + (size_t)M*C;            // 3C*C
    u16* wpb  = wqb  + (size_t)3*C*C;          // C*C
    u16* qkvb = wpb  + (size_t)C*C;            // M*3C
    u16* aob  = qkvb + (size_t)M*3*C;          // M*C

    cvt_all<<<dim3((N4X + N4Q + N4P) / 256), 256, 0, stream>>>(x, w_qkv, w_proj, xb, wqb, wpb);

    gemm_bt<<<dim3(3*C/128, M/128), 256, 0, stream>>>(xb, wqb, qkvb, nullptr, nullptr, M, 3*C, C);
    attn_v7<<<dim3(512), 256, 0, stream>>>(qkvb, mask, aob);
    gemm_bt64<<<dim3(C/128, M/64), 256, 0, stream>>>(aob, wpb, out, b_proj, M, C, C);
}

// Round 11
// 150.313 us; speedup vs baseline: 1.0444x; 1.0444x over previous
//
#include <hip/hip_runtime.h>

typedef unsigned short u16;
typedef unsigned int   u32;
typedef unsigned long long u64;
typedef short  short8 __attribute__((ext_vector_type(8)));
typedef float  f32x2  __attribute__((ext_vector_type(2)));
typedef float  f32x4  __attribute__((ext_vector_type(4)));
typedef float  f32x16 __attribute__((ext_vector_type(16)));
typedef u16    u16x4  __attribute__((ext_vector_type(4)));

__device__ __forceinline__ u16 f2b(float f) {
    u32 u = __float_as_uint(f);
    u32 r = (u + 0x7fffu + ((u >> 16) & 1u)) >> 16;  // RNE to bf16
    return (u16)r;
}

__device__ __forceinline__ u32 cvtpk(float a, float b) {
    u32 r;
    asm("v_cvt_pk_bf16_f32 %0, %1, %2" : "=v"(r) : "v"(a), "v"(b));
    return r;  // lo = bf16(a), hi = bf16(b)
}

__device__ __forceinline__ float ex2(float x) {   // 2^x, native v_exp_f32
    float r;
    asm("v_exp_f32 %0, %1" : "=v"(r) : "v"(x));
    return r;
}

__device__ __forceinline__ f32x2 pkfma(f32x2 a, f32x2 b, f32x2 c) {  // a*b+c per half
    f32x2 d;
    asm("v_pk_fma_f32 %0, %1, %2, %3" : "=v"(d) : "v"(a), "v"(b), "v"(c));
    return d;
}

// swap a's upper 32 lanes with c's lower 32 lanes
__device__ __forceinline__ void pl32swap(u32& a, u32& c) {
    asm("v_permlane32_swap_b32 %0, %1" : "+v"(a), "+v"(c));
}

__device__ __forceinline__ void gload_lds16(const void* g, void* l) {
    __builtin_amdgcn_global_load_lds(
        (const __attribute__((address_space(1))) u32*)g,
        (__attribute__((address_space(3))) u32*)l,
        16, 0, 0);
}

// ---------------- fused fp32 -> bf16 casts (one launch) ----------------
#define N4X 1048576   // 4096*1024/4
#define N4Q  786432   // 3*1024*1024/4
#define N4P  262144   // 1024*1024/4
__global__ __launch_bounds__(256) void cvt_all(
    const float* __restrict__ x, const float* __restrict__ wq, const float* __restrict__ wp,
    u16* __restrict__ xb, u16* __restrict__ wqb, u16* __restrict__ wpb)
{
    const int i = blockIdx.x * 256 + threadIdx.x;
    const float* src; u16* dst; int j;
    if (i < N4X)            { src = x;  dst = xb;  j = i; }
    else if (i < N4X + N4Q) { src = wq; dst = wqb; j = i - N4X; }
    else                    { src = wp; dst = wpb; j = i - N4X - N4Q; }
    float4 v = ((const float4*)src)[j];
    u16x4 r = { f2b(v.x), f2b(v.y), f2b(v.z), f2b(v.w) };
    ((u16x4*)dst)[j] = r;
}

// ---------------- deep-pipelined C = A @ B^T ----------------
// BM=256, BN=128, BK=64. 8 waves (512 thr) as 4M x 2N, wave-tile 64x64 = 4x4 frags.
// LDS: 3-buffer ring (144 KB, 1 block/CU, 2 waves/SIMD). Tile kt+2 staged during
// iter kt via global_load_lds with pre-swizzled source (chunk ^= row&7, attn-verified);
// ONE barrier/iter with counted vmcnt(6) -- prefetch stays a full iteration ahead.
__global__ __launch_bounds__(512, 2) void gemm_big(
    const u16* __restrict__ A, const u16* __restrict__ Bm,
    u16* __restrict__ Cb, float* __restrict__ Cf, const float* __restrict__ bias,
    int M, int N, int K)
{
    __shared__ __align__(16) u16 LA[3][256*64];   // 96 KB
    __shared__ __align__(16) u16 LB[3][128*64];   // 48 KB

    const int t = threadIdx.x;
    const int w = t >> 6, lane = t & 63;
    const int l15 = lane & 15, lg = lane >> 4;
    const int wr = w & 3, wc = w >> 2;            // M quadrant (64 rows), N half (64 cols)

    // XCD-contiguous block decode (grid % 8 == 0 for both call sites)
    const int cpx = (int)gridDim.x >> 3;
    const int wid = (blockIdx.x & 7) * cpx + (blockIdx.x >> 3);
    const int NB = N >> 7;                        // N/128
    const int m0 = (wid / NB) * 256, n0 = (wid % NB) * 128;

    // staging roles
    const int rowInG = lane >> 3;                               // 0..7
    const int sc     = ((lane & 7) ^ rowInG) * 8;               // inverse-swizzled src chunk
    const u16* aSrc = A  + (size_t)(m0 + w*32 + rowInG) * K + sc;
    const u16* bSrc = Bm + (size_t)(n0 + w*16 + rowInG) * K + sc;

    // frag-read swizzled chunk offsets (row&7 == l15&7 for 16-aligned row bases)
    const int ck0 = ( lg      ^ (l15 & 7)) * 8;
    const int ck1 = ((4 + lg) ^ (l15 & 7)) * 8;

    f32x4 acc[4][4] = {};

    #define STAGE_A(KT, BUF) do {                                            \
        const u16* _s = aSrc + (size_t)(KT) * 64;                            \
        u16* _d = &LA[BUF][w * 2048];                                        \
        _Pragma("unroll")                                                    \
        for (int g = 0; g < 4; ++g)                                          \
            gload_lds16(_s + (size_t)g * 8 * (size_t)K, _d + g * 512);       \
    } while (0)
    #define STAGE_B(KT, BUF) do {                                            \
        const u16* _s = bSrc + (size_t)(KT) * 64;                            \
        u16* _d = &LB[BUF][w * 1024];                                        \
        _Pragma("unroll")                                                    \
        for (int g = 0; g < 2; ++g)                                          \
            gload_lds16(_s + (size_t)g * 8 * (size_t)K, _d + g * 512);       \
    } while (0)

    // ---- prologue: stage tiles 0 and 1 ----
    STAGE_A(0, 0); STAGE_B(0, 0);
    STAGE_A(1, 1); STAGE_B(1, 1);
    asm volatile("s_waitcnt vmcnt(6)" ::: "memory");   // tile 0 landed
    __builtin_amdgcn_s_barrier();
    __builtin_amdgcn_sched_barrier(0);

    const int NKT = K >> 6;                       // 16 for K=1024
    int bufC = 0;
    for (int kt = 0; kt < NKT; ++kt) {
        const int bufN = (bufC + 2 >= 3) ? bufC - 1 : bufC + 2;
        const u16* __restrict__ lA = &LA[bufC][0];
        const u16* __restrict__ lB = &LB[bufC][0];

        // ---- phase 0: issue A(kt+2), read B frags + A rows 0-1, 16 MFMA ----
        if (kt < NKT - 2) STAGE_A(kt + 2, bufN);
        short8 bfr[4][2], afA[2][2];
        #pragma unroll
        for (int ni = 0; ni < 4; ++ni) {
            const int rb = (wc*64 + ni*16 + l15) * 64;
            bfr[ni][0] = *(const short8*)&lB[rb + ck0];
            bfr[ni][1] = *(const short8*)&lB[rb + ck1];
        }
        #pragma unroll
        for (int mi = 0; mi < 2; ++mi) {
            const int ra = (wr*64 + mi*16 + l15) * 64;
            afA[mi][0] = *(const short8*)&lA[ra + ck0];
            afA[mi][1] = *(const short8*)&lA[ra + ck1];
        }
        __builtin_amdgcn_s_setprio(1);
        #pragma unroll
        for (int mi = 0; mi < 2; ++mi)
            #pragma unroll
            for (int ni = 0; ni < 4; ++ni) {
                acc[mi][ni] = __builtin_amdgcn_mfma_f32_16x16x32_bf16(afA[mi][0], bfr[ni][0], acc[mi][ni], 0, 0, 0);
                acc[mi][ni] = __builtin_amdgcn_mfma_f32_16x16x32_bf16(afA[mi][1], bfr[ni][1], acc[mi][ni], 0, 0, 0);
            }
        __builtin_amdgcn_s_setprio(0);

        // ---- phase 1: issue B(kt+2), read A rows 2-3, 16 MFMA ----
        if (kt < NKT - 2) STAGE_B(kt + 2, bufN);
        short8 afB[2][2];
        #pragma unroll
        for (int mi = 0; mi < 2; ++mi) {
            const int ra = (wr*64 + (mi+2)*16 + l15) * 64;
            afB[mi][0] = *(const short8*)&lA[ra + ck0];
            afB[mi][1] = *(const short8*)&lA[ra + ck1];
        }
        __builtin_amdgcn_s_setprio(1);
        #pragma unroll
        for (int mi = 0; mi < 2; ++mi)
            #pragma unroll
            for (int ni = 0; ni < 4; ++ni) {
                acc[mi+2][ni] = __builtin_amdgcn_mfma_f32_16x16x32_bf16(afB[mi][0], bfr[ni][0], acc[mi+2][ni], 0, 0, 0);
                acc[mi+2][ni] = __builtin_amdgcn_mfma_f32_16x16x32_bf16(afB[mi][1], bfr[ni][1], acc[mi+2][ni], 0, 0, 0);
            }
        __builtin_amdgcn_s_setprio(0);

        // ---- end-of-iter: counted vmcnt (tile kt+1 landed), raw barrier ----
        if (kt < NKT - 1) {
            if (kt < NKT - 2) asm volatile("s_waitcnt vmcnt(6) lgkmcnt(0)" ::: "memory");
            else              asm volatile("s_waitcnt vmcnt(0) lgkmcnt(0)" ::: "memory");
            __builtin_amdgcn_s_barrier();
            __builtin_amdgcn_sched_barrier(0);
        }
        bufC = (bufC + 1 >= 3) ? 0 : bufC + 1;
    }
    #undef STAGE_A
    #undef STAGE_B

    // ---- epilogue ----
    #pragma unroll
    for (int mi = 0; mi < 4; ++mi) {
        #pragma unroll
        for (int ni = 0; ni < 4; ++ni) {
            const int row = m0 + wr*64 + mi*16 + lg*4;
            const int col = n0 + wc*64 + ni*16 + l15;
            if (Cb) {
                #pragma unroll
                for (int r = 0; r < 4; ++r)
                    Cb[(size_t)(row+r)*N + col] = f2b(acc[mi][ni][r]);
            } else {
                const float bv = bias ? bias[col] : 0.f;
                #pragma unroll
                for (int r = 0; r < 4; ++r)
                    Cf[(size_t)(row+r)*N + col] = acc[mi][ni][r] + bv;
            }
        }
    }
}

// ---------------- fused masked flash attention v6 (round-9 verified, 79.5 us) ----------------
__global__ __launch_bounds__(256) void attn_v6(
    const u16* __restrict__ qkv,   // [B*N][3072] bf16
    const int* __restrict__ mask,  // [B*N]
    u16* __restrict__ aout)        // [B*N][1024] bf16
{
    __shared__ __align__(16) u16 Ks[64*64];   // [kv][d], chunk ^= kv&7
    __shared__ __align__(16) u16 Vt[64*64];   // [d][kv], chunk ^= (d^(d>>3))&7

    const int t = threadIdx.x, w = t >> 6, lane = t & 63;
    const int l31 = lane & 31, hi = lane >> 5;

    const int wid = ((blockIdx.x & 7) << 6) | (blockIdx.x >> 3);   // XCD-contiguous
    const int qt = wid & 15, h = (wid >> 4) & 15, b = wid >> 8;
    const int q0 = qt * 128 + w * 32;

    const size_t qrow = (size_t)(b*2048 + q0 + l31);
    short8 qf[4];
    #pragma unroll
    for (int i = 0; i < 4; ++i)
        qf[i] = *(const short8*)&qkv[qrow*3072 + h*64 + i*16 + hi*8];
    const int mq = mask[b*2048 + q0 + l31];
    const float qs2 = mq ? 0.18033688011f : 0.f;   // 0.125 * log2(e); 0 -> uniform row

    union { u32 u[4]; short8 s; } qe;
    qe.u[0] = hi ? 0u : 0x3F80u;   // bf16 1.0 in k-slot 0
    qe.u[1] = 0; qe.u[2] = 0; qe.u[3] = 0;

    float m2 = -3e38f, l_run = 0.f;    // m2 in log2-scaled units
    f32x16 oacc[2] = {};

    const int vrr = t >> 3, vc8 = t & 7;
    short8 vreg0 = *(const short8*)&qkv[(size_t)(b*2048 +      vrr)*3072 + 2048 + h*64 + vc8*8];
    short8 vreg1 = *(const short8*)&qkv[(size_t)(b*2048 + 32 + vrr)*3072 + 2048 + h*64 + vc8*8];

    for (int kv0 = 0; kv0 < 2048; kv0 += 64) {
        __syncthreads();
        #pragma unroll
        for (int p = 0; p < 2; ++p) {
            const int kv = p*32 + vrr;
            const int kvhi = kv >> 3, kvlo = kv & 7;
            const short8 v = p ? vreg1 : vreg0;
            #pragma unroll
            for (int j = 0; j < 8; ++j)
                Vt[(vc8*8 + j)*64 + ((kvhi ^ ((j ^ vc8) & 7)) << 3) + kvlo] = (u16)v[j];
        }
        #pragma unroll
        for (int i = 0; i < 2; ++i) {
            const int row = w*16 + i*8 + (lane >> 3);
            const int scK = (lane & 7) ^ (lane >> 3);
            gload_lds16(&qkv[(size_t)(b*2048 + kv0 + row)*3072 + 1024 + h*64 + scK*8],
                        &Ks[(w*16 + i*8)*64]);
        }
        const u64 bal = __ballot(mask[b*2048 + kv0 + lane] != 0);
        const u32 mwA = (u32)bal, mwB = (u32)(bal >> 32);
        __syncthreads();

        if (kv0 + 64 < 2048) {
            vreg0 = *(const short8*)&qkv[(size_t)(b*2048 + kv0+64 + vrr)*3072 + 2048 + h*64 + vc8*8];
            vreg1 = *(const short8*)&qkv[(size_t)(b*2048 + kv0+96 + vrr)*3072 + 2048 + h*64 + vc8*8];
        }

        // ---- S^T: two 32x32 subtiles + mask-bias k-step ----
        f32x16 st0 = {}, st1 = {};
        __builtin_amdgcn_s_setprio(1);
        #pragma unroll
        for (int kd = 0; kd < 4; ++kd) {
            const int c = (2*kd + hi) ^ (l31 & 7);
            short8 kf0 = *(const short8*)&Ks[ l31      *64 + c*8];
            short8 kf1 = *(const short8*)&Ks[(32 + l31)*64 + c*8];
            st0 = __builtin_amdgcn_mfma_f32_32x32x16_bf16(kf0, qf[kd], st0, 0, 0, 0);
            st1 = __builtin_amdgcn_mfma_f32_32x32x16_bf16(kf1, qf[kd], st1, 0, 0, 0);
        }
        {
            union { u32 u[4]; short8 s; } ba0, ba1;
            ba0.u[0] = (((mwA >> l31) & 1u) | (u32)hi) ? 0u : 0xFF7Fu;  // bf16 -3.3895e38
            ba1.u[0] = (((mwB >> l31) & 1u) | (u32)hi) ? 0u : 0xFF7Fu;
            ba0.u[1] = 0; ba0.u[2] = 0; ba0.u[3] = 0;
            ba1.u[1] = 0; ba1.u[2] = 0; ba1.u[3] = 0;
            st0 = __builtin_amdgcn_mfma_f32_32x32x16_bf16(ba0.s, qe.s, st0, 0, 0, 0);
            st1 = __builtin_amdgcn_mfma_f32_32x32x16_bf16(ba1.s, qe.s, st1, 0, 0, 0);
        }
        __builtin_amdgcn_s_setprio(0);

        // ---- raw tile max ----
        float pm0 = -3e38f, pm1 = -3e38f, pm2 = -3e38f, pm3 = -3e38f;
        #pragma unroll
        for (int r = 0; r < 16; r += 4) {
            pm0 = fmaxf(pm0, fmaxf(st0[r],   st1[r]));
            pm1 = fmaxf(pm1, fmaxf(st0[r+1], st1[r+1]));
            pm2 = fmaxf(pm2, fmaxf(st0[r+2], st1[r+2]));
            pm3 = fmaxf(pm3, fmaxf(st0[r+3], st1[r+3]));
        }
        const float pmx = fmaxf(fmaxf(pm0, pm1), fmaxf(pm2, pm3));

        // ---- defer-max: full rescale only when max grew past THR ----
        if (__any(fmaf(pmx, qs2, -m2) > 11.5f)) {
            float pml = pmx * qs2;
            pml = fmaxf(pml, __shfl_xor(pml, 32));
            const float m_new = fmaxf(m2, pml);
            const float alpha = ex2(m2 - m_new);
            l_run *= alpha;
            #pragma unroll
            for (int r = 0; r < 16; ++r) {
                const int pat = (r & 3) + 8*(r >> 2);
                const float ar = __shfl(alpha, pat + 4*hi);
                oacc[0][r] *= ar; oacc[1][r] *= ar;
            }
            m2 = m_new;
        }

        // ---- p = exp2(pk_fma(st, qs2, -m2)), fused into bf16 pack ----
        const float nm = -m2;
        const f32x2 qv = { qs2, qs2 };
        const f32x2 nv = { nm, nm };
        float rs0 = 0.f, rs1 = 0.f;
        u32 o_[16];
        #pragma unroll
        for (int i = 0; i < 8; ++i) {
            f32x2 s0p = { st0[2*i], st0[2*i+1] };
            f32x2 s1p = { st1[2*i], st1[2*i+1] };
            const f32x2 d0 = pkfma(s0p, qv, nv);
            const f32x2 d1 = pkfma(s1p, qv, nv);
            const float p0 = ex2(d0.x), p1 = ex2(d0.y);
            const float p2 = ex2(d1.x), p3 = ex2(d1.y);
            o_[i]     = cvtpk(p0, p1);
            o_[8 + i] = cvtpk(p2, p3);
            rs0 += p0 + p1;
            rs1 += p2 + p3;
        }
        float rs = rs0 + rs1;
        rs += __shfl_xor(rs, 32);
        l_run += rs;

        // ---- PV: O += P @ V (half-swap via permlane32_swap) ----
        __builtin_amdgcn_s_setprio(1);
        #pragma unroll
        for (int kk = 0; kk < 4; ++kk) {
            const int base = (kk >> 1)*8 + (kk & 1)*4;
            u32 a0 = o_[base],   c0 = o_[base+2];
            u32 a1 = o_[base+1], c1 = o_[base+3];
            pl32swap(a0, c0);
            pl32swap(a1, c1);
            union { u32 u[4]; short8 s; } pa;
            pa.u[0] = a0; pa.u[1] = a1; pa.u[2] = c0; pa.u[3] = c1;
            #pragma unroll
            for (int dt = 0; dt < 2; ++dt) {
                const int d = dt*32 + l31;
                const int c = (2*kk + hi) ^ ((d ^ (d >> 3)) & 7);
                short8 vf = *(const short8*)&Vt[d*64 + c*8];
                oacc[dt] = __builtin_amdgcn_mfma_f32_32x32x16_bf16(pa.s, vf, oacc[dt], 0, 0, 0);
            }
        }
        __builtin_amdgcn_s_setprio(0);
    }

    const float inv = 1.f / l_run;
    #pragma unroll
    for (int r = 0; r < 16; ++r) {
        const int pat = (r & 3) + 8*(r >> 2);
        const float ir = __shfl(inv, pat + 4*hi);
        const size_t rowg = (size_t)(b*2048 + q0 + pat + 4*hi);
        aout[rowg*1024 + h*64 +      l31] = f2b(oacc[0][r] * ir);
        aout[rowg*1024 + h*64 + 32 + l31] = f2b(oacc[1][r] * ir);
    }
}

extern "C" void kernel_launch(void* const* d_in, const int* in_sizes, int n_in,
                              void* d_out, int out_size, void* d_ws, size_t ws_size,
                              hipStream_t stream)
{
    (void)in_sizes; (void)n_in; (void)out_size; (void)ws_size;
    const float* x      = (const float*)d_in[0];
    const int*   mask   = (const int*)  d_in[1];
    const float* w_qkv  = (const float*)d_in[2];
    const float* w_proj = (const float*)d_in[3];
    const float* b_proj = (const float*)d_in[4];
    float* out = (float*)d_out;

    const int M = 4096;   // B*N
    const int C = 1024;

    u16* xb   = (u16*)d_ws;                    // M*C
    u16* wqb  = xb   + (size_t)M*C;            // 3C*C
    u16* wpb  = wqb  + (size_t)3*C*C;          // C*C
    u16* qkvb = wpb  + (size_t)C*C;            // M*3C
    u16* aob  = qkvb + (size_t)M*3*C;          // M*C

    cvt_all<<<dim3((N4X + N4Q + N4P) / 256), 256, 0, stream>>>(x, w_qkv, w_proj, xb, wqb, wpb);

    gemm_big<<<dim3((M/256)*(3*C/128)), 512, 0, stream>>>(xb, wqb, qkvb, nullptr, nullptr, M, 3*C, C);
    attn_v6<<<dim3(512), 256, 0, stream>>>(qkvb, mask, aob);
    gemm_big<<<dim3((M/256)*(C/128)), 512, 0, stream>>>(aob, wpb, nullptr, out, b_proj, M, C, C);
}